// Round 1
// baseline (561.951 us; speedup 1.0000x reference)
//
#include <hip/hip_runtime.h>

#define B_ 4
#define C_ 4
#define V_ 262144
#define F_ 64
#define K_ 100
#define THETA 0.9f
#define TAU_ 0.1f
#define CAP_ 6144

// ---------------- workspace layout (bytes) ----------------
// cs     : 0      .. 1024    (C*F floats, [c][f])
// cnt    : 1024   .. 1040    (C floats)
// hist   : 2048   .. 6144    (B*256 u32)
// ctrl   : 6144   .. 6176    (B*2 u32: T1, n_above)
// ccount : 6208   .. 6224    (B u32)
// idxout : 6272   .. 7872    (B*K u32)
// cbits  : 8192   .. 106496  (B*CAP u32)
// cidx   : 106496 .. 204800  (B*CAP u32)

__global__ void k_init(float* cs, float* cnt, unsigned* hist, unsigned* ccount) {
    int t = blockIdx.x * blockDim.x + threadIdx.x;
    if (t < C_ * F_) cs[t] = 0.f;
    if (t < C_) cnt[t] = 0.f;
    if (t < B_ * 256) hist[t] = 0u;
    if (t < B_) ccount[t] = 0u;
}

// class_sum[c][f] += emb[b,f,v] * (y[b,c,v]>0); count[c] += mask
// grid: B*256 blocks (256 chunks of 1024 v per b), block 256 threads
// thread: f = tid>>2 (0..63), j = tid&3; float4 over v.
__global__ __launch_bounds__(256) void k_class_sum(const float* __restrict__ emb,
                                                   const int* __restrict__ y,
                                                   float* __restrict__ cs,
                                                   float* __restrict__ cnt) {
    int b = blockIdx.x >> 8;
    int chunk = blockIdx.x & 255;
    int base = chunk << 10;  // *1024
    int tid = threadIdx.x;
    int f = tid >> 2, j = tid & 3;

    const float4* er = (const float4*)(emb + ((size_t)(b * F_ + f)) * V_ + base);
    const int4* y0 = (const int4*)(y + ((size_t)(b * C_ + 0)) * V_ + base);
    const int4* y1 = (const int4*)(y + ((size_t)(b * C_ + 1)) * V_ + base);
    const int4* y2 = (const int4*)(y + ((size_t)(b * C_ + 2)) * V_ + base);
    const int4* y3 = (const int4*)(y + ((size_t)(b * C_ + 3)) * V_ + base);

    float a0 = 0.f, a1 = 0.f, a2 = 0.f, a3 = 0.f;
    float n0 = 0.f, n1 = 0.f, n2 = 0.f, n3 = 0.f;

    for (int it = 0; it < 64; ++it) {
        int v4 = j + (it << 2);
        float4 e = er[v4];
        int4 ya = y0[v4], yb = y1[v4], yc = y2[v4], yd = y3[v4];
        a0 += (ya.x > 0 ? e.x : 0.f) + (ya.y > 0 ? e.y : 0.f) + (ya.z > 0 ? e.z : 0.f) + (ya.w > 0 ? e.w : 0.f);
        a1 += (yb.x > 0 ? e.x : 0.f) + (yb.y > 0 ? e.y : 0.f) + (yb.z > 0 ? e.z : 0.f) + (yb.w > 0 ? e.w : 0.f);
        a2 += (yc.x > 0 ? e.x : 0.f) + (yc.y > 0 ? e.y : 0.f) + (yc.z > 0 ? e.z : 0.f) + (yc.w > 0 ? e.w : 0.f);
        a3 += (yd.x > 0 ? e.x : 0.f) + (yd.y > 0 ? e.y : 0.f) + (yd.z > 0 ? e.z : 0.f) + (yd.w > 0 ? e.w : 0.f);
        if (f == 0) {
            n0 += (ya.x > 0 ? 1.f : 0.f) + (ya.y > 0 ? 1.f : 0.f) + (ya.z > 0 ? 1.f : 0.f) + (ya.w > 0 ? 1.f : 0.f);
            n1 += (yb.x > 0 ? 1.f : 0.f) + (yb.y > 0 ? 1.f : 0.f) + (yb.z > 0 ? 1.f : 0.f) + (yb.w > 0 ? 1.f : 0.f);
            n2 += (yc.x > 0 ? 1.f : 0.f) + (yc.y > 0 ? 1.f : 0.f) + (yc.z > 0 ? 1.f : 0.f) + (yc.w > 0 ? 1.f : 0.f);
            n3 += (yd.x > 0 ? 1.f : 0.f) + (yd.y > 0 ? 1.f : 0.f) + (yd.z > 0 ? 1.f : 0.f) + (yd.w > 0 ? 1.f : 0.f);
        }
    }

    __shared__ float s[256][4];
    s[tid][0] = a0; s[tid][1] = a1; s[tid][2] = a2; s[tid][3] = a3;
    __shared__ float scn[4][4];
    if (f == 0) { scn[j][0] = n0; scn[j][1] = n1; scn[j][2] = n2; scn[j][3] = n3; }
    __syncthreads();

    if (j == 0) {
        for (int c = 0; c < 4; ++c) {
            float v = s[tid][c] + s[tid + 1][c] + s[tid + 2][c] + s[tid + 3][c];
            atomicAdd(&cs[c * F_ + f], v);
        }
    }
    if (tid < 4) {
        float t4 = scn[0][tid] + scn[1][tid] + scn[2][tid] + scn[3][tid];
        atomicAdd(&cnt[tid], t4);
    }
}

// histogram of top-8 bits of w = prod_c proba[b,c,v]
__global__ __launch_bounds__(256) void k_hist(const float* __restrict__ proba, unsigned* __restrict__ hist) {
    __shared__ unsigned lh[256];
    int tid = threadIdx.x;
    lh[tid] = 0u;
    __syncthreads();
    int b = blockIdx.x >> 8;
    int chunk = blockIdx.x & 255;
    int base = chunk << 10;
    const float* p0 = proba + (size_t)(b * C_) * V_;
    for (int it = 0; it < 4; ++it) {
        int v = base + tid + (it << 8);
        float w = ((p0[v] * p0[v + V_]) * p0[v + 2 * V_]) * p0[v + 3 * V_];
        unsigned bits = __float_as_uint(w);
        atomicAdd(&lh[bits >> 24], 1u);
    }
    __syncthreads();
    if (lh[tid]) atomicAdd(&hist[b * 256 + tid], lh[tid]);
}

__global__ void k_thresh(const unsigned* __restrict__ hist, unsigned* __restrict__ ctrl) {
    int b = threadIdx.x;
    if (b >= B_) return;
    const unsigned* h = hist + b * 256;
    unsigned cum = 0;
    int bin = 255;
    for (; bin >= 0; --bin) {
        unsigned nb = cum + h[bin];
        if (nb >= K_) { ctrl[b * 2] = (unsigned)bin; ctrl[b * 2 + 1] = cum; return; }
        cum = nb;
    }
    ctrl[b * 2] = 0u; ctrl[b * 2 + 1] = cum;
}

__global__ __launch_bounds__(256) void k_collect(const float* __restrict__ proba,
                                                 const unsigned* __restrict__ ctrl,
                                                 unsigned* __restrict__ ccount,
                                                 unsigned* __restrict__ cbits,
                                                 unsigned* __restrict__ cidx) {
    int b = blockIdx.x >> 8;
    int chunk = blockIdx.x & 255;
    int base = chunk << 10;
    int tid = threadIdx.x;
    unsigned T1 = ctrl[b * 2];
    const float* p0 = proba + (size_t)(b * C_) * V_;
    for (int it = 0; it < 4; ++it) {
        int v = base + tid + (it << 8);
        float w = ((p0[v] * p0[v + V_]) * p0[v + 2 * V_]) * p0[v + 3 * V_];
        unsigned bits = __float_as_uint(w);
        if ((bits >> 24) >= T1) {
            unsigned pos = atomicAdd(&ccount[b], 1u);
            if (pos < CAP_) { cbits[b * CAP_ + pos] = bits; cidx[b * CAP_ + pos] = (unsigned)v; }
        }
    }
}

// exact top-K selection: key = (bits desc, index asc)
__global__ __launch_bounds__(256) void k_select(const unsigned* __restrict__ ccount,
                                                const unsigned* __restrict__ cbits,
                                                const unsigned* __restrict__ cidx,
                                                unsigned* __restrict__ idxout) {
    __shared__ unsigned sb[CAP_];
    __shared__ unsigned si[CAP_];
    __shared__ unsigned long long rk[256];
    int b = blockIdx.x;
    int tid = threadIdx.x;
    unsigned nc = ccount[b];
    int n = (int)(nc < CAP_ ? nc : CAP_);
    for (int i = tid; i < CAP_; i += 256) {
        if (i < n) { sb[i] = cbits[b * CAP_ + i]; si[i] = cidx[b * CAP_ + i]; }
        else { sb[i] = 0u; si[i] = 0xFFFFFFFFu; }
    }
    __syncthreads();
    for (int k = 0; k < K_; ++k) {
        unsigned long long mk = 0ull;
        for (int i = tid; i < CAP_; i += 256) {
            unsigned long long key = ((unsigned long long)sb[i] << 32) | (unsigned)(0xFFFFFFFFu - si[i]);
            if (key > mk) mk = key;
        }
        rk[tid] = mk;
        __syncthreads();
        for (int s = 128; s > 0; s >>= 1) {
            if (tid < s && rk[tid + s] > rk[tid]) rk[tid] = rk[tid + s];
            __syncthreads();
        }
        unsigned long long wk = rk[0];
        if (tid == 0) idxout[b * K_ + k] = 0xFFFFFFFFu - (unsigned)(wk & 0xFFFFFFFFu);
        __syncthreads();
        for (int i = tid; i < CAP_; i += 256) {
            unsigned long long key = ((unsigned long long)sb[i] << 32) | (unsigned)(0xFFFFFFFFu - si[i]);
            if (key == wk) { sb[i] = 0u; si[i] = 0xFFFFFFFFu; }
        }
        __syncthreads();
    }
}

// final: one wave (64 lanes = F) per (b,k)
__global__ __launch_bounds__(64) void k_final(const float* __restrict__ emb,
                                              const int* __restrict__ y,
                                              const float* __restrict__ avg,
                                              const float* __restrict__ cs,
                                              const float* __restrict__ cnt,
                                              const unsigned* __restrict__ idxout,
                                              float* __restrict__ out) {
    int blk = blockIdx.x;
    int b = blk / K_;
    int k = blk % K_;
    int lane = threadIdx.x;
    unsigned v = idxout[b * K_ + k];

    float e = emb[((size_t)(b * F_ + lane)) * V_ + v];

    int y0v = y[((size_t)(b * C_ + 0)) * V_ + v];
    int y1v = y[((size_t)(b * C_ + 1)) * V_ + v];
    int y2v = y[((size_t)(b * C_ + 2)) * V_ + v];
    int y3v = y[((size_t)(b * C_ + 3)) * V_ + v];
    int cm = (y0v > 0) ? 0 : ((y1v > 0) ? 1 : ((y2v > 0) ? 2 : ((y3v > 0) ? 3 : 0)));
    float sel = (cm == 0) ? 1.f : 0.f;

    float t = e / TAU_;
    float ssum = 0.f;
    #pragma unroll
    for (int c = 1; c < 4; ++c) {
        float cc = cnt[c];
        float mean = cs[c * F_ + lane] / fmaxf(cc, 1.f);
        float av = avg[c * F_ + lane];
        float nar = (cc > 0.f) ? (av * (1.f - THETA) + mean * THETA) : av;
        ssum += expf(t * nar);
    }
    float term = -logf(ssum);
    #pragma unroll
    for (int o = 32; o > 0; o >>= 1) term += __shfl_down(term, o, 64);
    if (lane == 0) out[b * K_ + k] = term * sel;
}

extern "C" void kernel_launch(void* const* d_in, const int* in_sizes, int n_in,
                              void* d_out, int out_size, void* d_ws, size_t ws_size,
                              hipStream_t stream) {
    const float* proba = (const float*)d_in[0];
    const int* y = (const int*)d_in[1];
    const float* emb = (const float*)d_in[2];
    const float* avg = (const float*)d_in[3];
    float* out = (float*)d_out;

    char* ws = (char*)d_ws;
    float* cs = (float*)(ws + 0);
    float* cnt = (float*)(ws + 1024);
    unsigned* hist = (unsigned*)(ws + 2048);
    unsigned* ctrl = (unsigned*)(ws + 6144);
    unsigned* ccount = (unsigned*)(ws + 6208);
    unsigned* idxout = (unsigned*)(ws + 6272);
    unsigned* cbits = (unsigned*)(ws + 8192);
    unsigned* cidx = (unsigned*)(ws + 106496);

    k_init<<<4, 256, 0, stream>>>(cs, cnt, hist, ccount);
    k_class_sum<<<B_ * 256, 256, 0, stream>>>(emb, y, cs, cnt);
    k_hist<<<B_ * 256, 256, 0, stream>>>(proba, hist);
    k_thresh<<<1, 64, 0, stream>>>(hist, ctrl);
    k_collect<<<B_ * 256, 256, 0, stream>>>(proba, ctrl, ccount, cbits, cidx);
    k_select<<<B_, 256, 0, stream>>>(ccount, cbits, cidx, idxout);
    k_final<<<B_ * K_, 64, 0, stream>>>(emb, y, avg, cs, cnt, idxout, out);
}

// Round 2
// 185.460 us; speedup vs baseline: 3.0300x; 3.0300x over previous
//
#include <hip/hip_runtime.h>

#define B_ 4
#define C_ 4
#define V_ 262144
#define F_ 64
#define K_ 100
#define THETA 0.9f
#define TAU_ 0.1f
#define CAP2 4096

typedef unsigned long long ull;

// ---------------- workspace layout (bytes) ----------------
// cs     : 0      .. 1024    (C*F floats, [c][f])
// cnt    : 1024   .. 1040    (C floats)
// hist1  : 2048   .. 6144    (B*256 u32)
// hist2  : 6144   .. 10240   (B*256 u32)
// ctrl1  : 10240  .. 10272   (B*2 u32: T1, n_above)
// ctrl2  : 10272  .. 10304   (B*2 u32: P16, n_above2)
// ccount : 10304  .. 10320   (B u32)
// idxout : 10368  .. 11968   (B*K u32)
// cbits  : 16384  .. 81920   (B*CAP2 u32)
// cidx   : 81920  .. 147456  (B*CAP2 u32)

__global__ void k_init(float* cs, float* cnt, unsigned* hist1, unsigned* hist2, unsigned* ccount) {
    int t = blockIdx.x * blockDim.x + threadIdx.x;
    if (t < C_ * F_) cs[t] = 0.f;
    if (t < C_) cnt[t] = 0.f;
    if (t < B_ * 256) { hist1[t] = 0u; hist2[t] = 0u; }
    if (t < B_) ccount[t] = 0u;
}

// class_sum[c][f] += emb[b,f,v] * (y[b,c,v]>0); count[c] += mask
__global__ __launch_bounds__(256) void k_class_sum(const float* __restrict__ emb,
                                                   const int* __restrict__ y,
                                                   float* __restrict__ cs,
                                                   float* __restrict__ cnt) {
    int b = blockIdx.x >> 8;
    int chunk = blockIdx.x & 255;
    int base = chunk << 10;
    int tid = threadIdx.x;
    int f = tid >> 2, j = tid & 3;

    const float4* er = (const float4*)(emb + ((size_t)(b * F_ + f)) * V_ + base);
    const int4* y0 = (const int4*)(y + ((size_t)(b * C_ + 0)) * V_ + base);
    const int4* y1 = (const int4*)(y + ((size_t)(b * C_ + 1)) * V_ + base);
    const int4* y2 = (const int4*)(y + ((size_t)(b * C_ + 2)) * V_ + base);
    const int4* y3 = (const int4*)(y + ((size_t)(b * C_ + 3)) * V_ + base);

    float a0 = 0.f, a1 = 0.f, a2 = 0.f, a3 = 0.f;
    float n0 = 0.f, n1 = 0.f, n2 = 0.f, n3 = 0.f;

    for (int it = 0; it < 64; ++it) {
        int v4 = j + (it << 2);
        float4 e = er[v4];
        int4 ya = y0[v4], yb = y1[v4], yc = y2[v4], yd = y3[v4];
        a0 += (ya.x > 0 ? e.x : 0.f) + (ya.y > 0 ? e.y : 0.f) + (ya.z > 0 ? e.z : 0.f) + (ya.w > 0 ? e.w : 0.f);
        a1 += (yb.x > 0 ? e.x : 0.f) + (yb.y > 0 ? e.y : 0.f) + (yb.z > 0 ? e.z : 0.f) + (yb.w > 0 ? e.w : 0.f);
        a2 += (yc.x > 0 ? e.x : 0.f) + (yc.y > 0 ? e.y : 0.f) + (yc.z > 0 ? e.z : 0.f) + (yc.w > 0 ? e.w : 0.f);
        a3 += (yd.x > 0 ? e.x : 0.f) + (yd.y > 0 ? e.y : 0.f) + (yd.z > 0 ? e.z : 0.f) + (yd.w > 0 ? e.w : 0.f);
        if (f == 0) {
            n0 += (ya.x > 0 ? 1.f : 0.f) + (ya.y > 0 ? 1.f : 0.f) + (ya.z > 0 ? 1.f : 0.f) + (ya.w > 0 ? 1.f : 0.f);
            n1 += (yb.x > 0 ? 1.f : 0.f) + (yb.y > 0 ? 1.f : 0.f) + (yb.z > 0 ? 1.f : 0.f) + (yb.w > 0 ? 1.f : 0.f);
            n2 += (yc.x > 0 ? 1.f : 0.f) + (yc.y > 0 ? 1.f : 0.f) + (yc.z > 0 ? 1.f : 0.f) + (yc.w > 0 ? 1.f : 0.f);
            n3 += (yd.x > 0 ? 1.f : 0.f) + (yd.y > 0 ? 1.f : 0.f) + (yd.z > 0 ? 1.f : 0.f) + (yd.w > 0 ? 1.f : 0.f);
        }
    }

    __shared__ float s[256][4];
    s[tid][0] = a0; s[tid][1] = a1; s[tid][2] = a2; s[tid][3] = a3;
    __shared__ float scn[4][4];
    if (f == 0) { scn[j][0] = n0; scn[j][1] = n1; scn[j][2] = n2; scn[j][3] = n3; }
    __syncthreads();

    if (j == 0) {
        for (int c = 0; c < 4; ++c) {
            float v = s[tid][c] + s[tid + 1][c] + s[tid + 2][c] + s[tid + 3][c];
            atomicAdd(&cs[c * F_ + f], v);
        }
    }
    if (tid < 4) {
        float t4 = scn[0][tid] + scn[1][tid] + scn[2][tid] + scn[3][tid];
        atomicAdd(&cnt[tid], t4);
    }
}

__device__ __forceinline__ float weight_of(const float* __restrict__ p0, int v) {
    return ((p0[v] * p0[v + V_]) * p0[v + 2 * V_]) * p0[v + 3 * V_];
}

// level-1 histogram: top-8 bits of w
__global__ __launch_bounds__(256) void k_hist1(const float* __restrict__ proba, unsigned* __restrict__ hist1) {
    __shared__ unsigned lh[256];
    int tid = threadIdx.x;
    lh[tid] = 0u;
    __syncthreads();
    int b = blockIdx.x >> 8;
    int base = (blockIdx.x & 255) << 10;
    const float* p0 = proba + (size_t)(b * C_) * V_;
    for (int it = 0; it < 4; ++it) {
        int v = base + tid + (it << 8);
        unsigned bits = __float_as_uint(weight_of(p0, v));
        atomicAdd(&lh[bits >> 24], 1u);
    }
    __syncthreads();
    if (lh[tid]) atomicAdd(&hist1[b * 256 + tid], lh[tid]);
}

// level-2 histogram: next 8 bits, only for elements in bin T1
__global__ __launch_bounds__(256) void k_hist2(const float* __restrict__ proba,
                                               const unsigned* __restrict__ ctrl1,
                                               unsigned* __restrict__ hist2) {
    __shared__ unsigned lh[256];
    int tid = threadIdx.x;
    lh[tid] = 0u;
    __syncthreads();
    int b = blockIdx.x >> 8;
    int base = (blockIdx.x & 255) << 10;
    unsigned T1 = ctrl1[b * 2];
    const float* p0 = proba + (size_t)(b * C_) * V_;
    for (int it = 0; it < 4; ++it) {
        int v = base + tid + (it << 8);
        unsigned bits = __float_as_uint(weight_of(p0, v));
        if ((bits >> 24) == T1) atomicAdd(&lh[(bits >> 16) & 0xFF], 1u);
    }
    __syncthreads();
    if (lh[tid]) atomicAdd(&hist2[b * 256 + tid], lh[tid]);
}

// wave-parallel threshold finder over a 256-bin histogram (descending).
// lvl==0: base=0, out {T1, n_above}.  lvl==1: base=ctrl_in[n_above], out {P16=(T1<<8)|T2, n_above2}.
__global__ __launch_bounds__(256) void k_thresh(const unsigned* __restrict__ hist,
                                                const unsigned* __restrict__ ctrl_in,
                                                unsigned* __restrict__ ctrl_out,
                                                int lvl) {
    int b = threadIdx.x >> 6;
    int lane = threadIdx.x & 63;
    const unsigned* h = hist + b * 256;
    unsigned base = lvl ? ctrl_in[b * 2 + 1] : 0u;
    int binbase = 255 - 4 * lane;
    unsigned c0 = h[binbase], c1 = h[binbase - 1], c2 = h[binbase - 2], c3 = h[binbase - 3];
    unsigned cnt4 = c0 + c1 + c2 + c3;
    unsigned pref = cnt4;
    #pragma unroll
    for (int o = 1; o < 64; o <<= 1) {
        unsigned u = __shfl_up(pref, o, 64);
        if (lane >= o) pref += u;
    }
    unsigned above = base + pref - cnt4;  // count strictly above this lane's bins
    unsigned t = above;
    int found = -1; unsigned nab = 0;
    if (t + c0 >= K_)                { found = binbase;     nab = t; }
    else if (t + c0 + c1 >= K_)      { found = binbase - 1; nab = t + c0; }
    else if (t + c0 + c1 + c2 >= K_) { found = binbase - 2; nab = t + c0 + c1; }
    else if (t + cnt4 >= K_)         { found = binbase - 3; nab = t + c0 + c1 + c2; }
    if (found >= 0 && above < K_) {
        ctrl_out[b * 2] = lvl ? ((ctrl_in[b * 2] << 8) | (unsigned)found) : (unsigned)found;
        ctrl_out[b * 2 + 1] = nab;
    }
}

// collect all candidates with (bits>>16) >= P16  (~K + one 16-bit bin)
__global__ __launch_bounds__(256) void k_collect(const float* __restrict__ proba,
                                                 const unsigned* __restrict__ ctrl2,
                                                 unsigned* __restrict__ ccount,
                                                 unsigned* __restrict__ cbits,
                                                 unsigned* __restrict__ cidx) {
    int b = blockIdx.x >> 8;
    int base = (blockIdx.x & 255) << 10;
    int tid = threadIdx.x;
    unsigned P16 = ctrl2[b * 2];
    const float* p0 = proba + (size_t)(b * C_) * V_;
    for (int it = 0; it < 4; ++it) {
        int v = base + tid + (it << 8);
        unsigned bits = __float_as_uint(weight_of(p0, v));
        if ((bits >> 16) >= P16) {
            unsigned pos = atomicAdd(&ccount[b], 1u);
            if (pos < CAP2) { cbits[b * CAP2 + pos] = bits; cidx[b * CAP2 + pos] = (unsigned)v; }
        }
    }
}

// exact top-K: one wave per b, lane-private LDS regions, zero barriers.
// key = (bits desc, idx asc)  == lax.top_k order for non-negative floats.
__global__ __launch_bounds__(64) void k_select(const unsigned* __restrict__ ccount,
                                               const unsigned* __restrict__ cbits,
                                               const unsigned* __restrict__ cidx,
                                               unsigned* __restrict__ idxout) {
    __shared__ ull keys[CAP2];
    int b = blockIdx.x;
    int lane = threadIdx.x;
    unsigned nc = ccount[b];
    int n = (int)(nc < CAP2 ? nc : CAP2);
    for (int i = lane; i < n; i += 64)
        keys[i] = ((ull)cbits[b * CAP2 + i] << 32) | (unsigned)(~cidx[b * CAP2 + i]);
    // lane i only ever touches keys[i], keys[i+64], ... -> no cross-lane LDS deps, no barriers.
    for (int k = 0; k < K_; ++k) {
        ull m = 0ull; int mslot = -1;
        for (int i = lane; i < n; i += 64) {
            ull key = keys[i];
            if (key > m) { m = key; mslot = i; }
        }
        ull lm = m;
        #pragma unroll
        for (int o = 1; o < 64; o <<= 1) {
            ull other = __shfl_xor(m, o, 64);
            if (other > m) m = other;
        }
        if (mslot >= 0 && lm == m) keys[mslot] = 0ull;  // unique keys -> exactly one lane
        if (lane == 0) idxout[b * K_ + k] = ~(unsigned)(m & 0xFFFFFFFFull);
    }
}

// final: one wave (64 lanes = F) per (b,k)
__global__ __launch_bounds__(64) void k_final(const float* __restrict__ emb,
                                              const int* __restrict__ y,
                                              const float* __restrict__ avg,
                                              const float* __restrict__ cs,
                                              const float* __restrict__ cnt,
                                              const unsigned* __restrict__ idxout,
                                              float* __restrict__ out) {
    int blk = blockIdx.x;
    int b = blk / K_;
    int k = blk % K_;
    int lane = threadIdx.x;
    unsigned v = idxout[b * K_ + k];

    float e = emb[((size_t)(b * F_ + lane)) * V_ + v];

    int y0v = y[((size_t)(b * C_ + 0)) * V_ + v];
    int y1v = y[((size_t)(b * C_ + 1)) * V_ + v];
    int y2v = y[((size_t)(b * C_ + 2)) * V_ + v];
    int y3v = y[((size_t)(b * C_ + 3)) * V_ + v];
    int cm = (y0v > 0) ? 0 : ((y1v > 0) ? 1 : ((y2v > 0) ? 2 : ((y3v > 0) ? 3 : 0)));
    float sel = (cm == 0) ? 1.f : 0.f;

    float t = e / TAU_;
    float ssum = 0.f;
    #pragma unroll
    for (int c = 1; c < 4; ++c) {
        float cc = cnt[c];
        float mean = cs[c * F_ + lane] / fmaxf(cc, 1.f);
        float av = avg[c * F_ + lane];
        float nar = (cc > 0.f) ? (av * (1.f - THETA) + mean * THETA) : av;
        ssum += expf(t * nar);
    }
    float term = -logf(ssum);
    #pragma unroll
    for (int o = 32; o > 0; o >>= 1) term += __shfl_down(term, o, 64);
    if (lane == 0) out[b * K_ + k] = term * sel;
}

extern "C" void kernel_launch(void* const* d_in, const int* in_sizes, int n_in,
                              void* d_out, int out_size, void* d_ws, size_t ws_size,
                              hipStream_t stream) {
    const float* proba = (const float*)d_in[0];
    const int* y = (const int*)d_in[1];
    const float* emb = (const float*)d_in[2];
    const float* avg = (const float*)d_in[3];
    float* out = (float*)d_out;

    char* ws = (char*)d_ws;
    float* cs = (float*)(ws + 0);
    float* cnt = (float*)(ws + 1024);
    unsigned* hist1 = (unsigned*)(ws + 2048);
    unsigned* hist2 = (unsigned*)(ws + 6144);
    unsigned* ctrl1 = (unsigned*)(ws + 10240);
    unsigned* ctrl2 = (unsigned*)(ws + 10272);
    unsigned* ccount = (unsigned*)(ws + 10304);
    unsigned* idxout = (unsigned*)(ws + 10368);
    unsigned* cbits = (unsigned*)(ws + 16384);
    unsigned* cidx = (unsigned*)(ws + 81920);

    k_init<<<4, 256, 0, stream>>>(cs, cnt, hist1, hist2, ccount);
    k_class_sum<<<B_ * 256, 256, 0, stream>>>(emb, y, cs, cnt);
    k_hist1<<<B_ * 256, 256, 0, stream>>>(proba, hist1);
    k_thresh<<<1, 256, 0, stream>>>(hist1, nullptr, ctrl1, 0);
    k_hist2<<<B_ * 256, 256, 0, stream>>>(proba, ctrl1, hist2);
    k_thresh<<<1, 256, 0, stream>>>(hist2, ctrl1, ctrl2, 1);
    k_collect<<<B_ * 256, 256, 0, stream>>>(proba, ctrl2, ccount, cbits, cidx);
    k_select<<<B_, 64, 0, stream>>>(ccount, cbits, cidx, idxout);
    k_final<<<B_ * K_, 64, 0, stream>>>(emb, y, avg, cs, cnt, idxout, out);
}